// Round 9
// baseline (678.825 us; speedup 1.0000x reference)
//
#include <hip/hip_runtime.h>
#include <hip/hip_fp16.h>

namespace {

constexpr int kUsers = 100000;
constexpr int kItems = 200000;
constexpr int kN     = kUsers + kItems;   // 300000
constexpr int kD     = 64;
constexpr int kNNZ   = 5000000;
constexpr int kB     = 16384;
constexpr int kRowsPerBkt = 2048;                       // rows per coarse bucket
constexpr int kNBKT  = (kN + kRowsPerBkt - 1) / kRowsPerBkt;  // 147
constexpr int kSEPB  = 4096;                            // edges per bucket_scatter block
constexpr int kCE    = 8192;                            // edges per finalize chunk
constexpr int kMC    = 5;                               // chunks per bucket
constexpr int kCap   = kMC * kCE;                       // 40960 slots/bucket (mean 34133, sd 185)
constexpr int kDB    = 64;                              // degree-sort bins (clamp 63)

__global__ void zero_i32(int* __restrict__ p, int n) {
  int i = blockIdx.x * blockDim.x + threadIdx.x;
  if (i < n) p[i] = 0;
}

// Counting-sort partition of 4096 edges into 147 coarse buckets; per-wave LDS
// histograms (4x147) cut same-address atomic serialization 4x. LDS staging so
// tmp writes go out in coalesced bucket-run bursts.
// Packed edge: .x = (rowlocal<<19)|col, .y = val bits.
__global__ void bucket_scatter(const int* __restrict__ row, const int* __restrict__ col,
                               const float* __restrict__ val, int* __restrict__ gpos,
                               int2* __restrict__ tmp) {
  __shared__ int hcnt[4][kNBKT];   // per-wave counts -> wave-exclusive offsets
  __shared__ int lofs[kNBKT];
  __shared__ int hbase[kNBKT];
  __shared__ int lds[256];
  __shared__ int2 se[kSEPB];
  __shared__ unsigned short sb[kSEPB];
  int t = threadIdx.x;
  int wv = t >> 6;
  long base = (long)blockIdx.x * kSEPB;
  int valid = (int)min((long)kSEPB, (long)kNNZ - base);
  for (int i = t; i < kNBKT; i += 256) {
    hcnt[0][i] = 0; hcnt[1][i] = 0; hcnt[2][i] = 0; hcnt[3][i] = 0;
  }
  __syncthreads();
  int pk[16], bk[16], rk[16];
  float v[16];
  bool ok[16];
#pragma unroll
  for (int j = 0; j < 16; ++j) {
    long i = base + j * 256 + t;
    ok[j] = (i < kNNZ);
    if (ok[j]) {
      int r = row[i];
      bk[j] = r >> 11;
      pk[j] = ((r & 2047) << 19) | col[i];
      v[j] = val[i];
      rk[j] = atomicAdd(&hcnt[wv][bk[j]], 1);
    }
  }
  __syncthreads();
  // per-bucket: wave-exclusive offsets + total; then block scan of totals
  int own = 0;
  if (t < kNBKT) {
    int c0 = hcnt[0][t], c1 = hcnt[1][t], c2 = hcnt[2][t], c3 = hcnt[3][t];
    hcnt[0][t] = 0; hcnt[1][t] = c0; hcnt[2][t] = c0 + c1; hcnt[3][t] = c0 + c1 + c2;
    own = c0 + c1 + c2 + c3;
  }
  lds[t] = own;
  __syncthreads();
  for (int o = 1; o < 256; o <<= 1) {
    int x = (t >= o) ? lds[t - o] : 0;
    __syncthreads();
    if (t >= o) lds[t] += x;
    __syncthreads();
  }
  if (t < kNBKT) {
    lofs[t] = lds[t] - own;
    hbase[t] = t * kCap + atomicAdd(&gpos[t], own);
  }
  __syncthreads();
  // place into LDS in bucket-sorted order
#pragma unroll
  for (int j = 0; j < 16; ++j) {
    if (ok[j]) {
      int pos = lofs[bk[j]] + hcnt[wv][bk[j]] + rk[j];
      se[pos] = make_int2(pk[j], __float_as_int(v[j]));
      sb[pos] = (unsigned short)bk[j];
    }
  }
  __syncthreads();
  // drain LDS sequentially -> coalesced global runs
#pragma unroll
  for (int j = 0; j < 16; ++j) {
    int pos = t + j * 256;
    if (pos < valid) {
      int b = sb[pos];
      tmp[hbase[b] + (pos - lofs[b])] = se[pos];
    }
  }
}

// Grid = kNBKT*kMC. Per-(bucket,chunk) 2048-row LDS histogram -> ctab.
__global__ void chunk_hist(const int* __restrict__ gpos, const int2* __restrict__ tmp,
                           int* __restrict__ ctab) {
  __shared__ int h[kRowsPerBkt];
  int b = blockIdx.x / kMC, c = blockIdx.x % kMC;
  int t = threadIdx.x;
  for (int i = t; i < kRowsPerBkt; i += 256) h[i] = 0;
  __syncthreads();
  int s = b * kCap + c * kCE;
  int e = b * kCap + gpos[b];
  if (s + kCE < e) e = s + kCE;
  for (int j = s + t; j < e; j += 256) atomicAdd(&h[tmp[j].x >> 19], 1);
  __syncthreads();
  int* dst = ctab + (size_t)blockIdx.x * kRowsPerBkt;
  for (int i = t; i < kRowsPerBkt; i += 256) dst[i] = h[i];
}

// Per-row totals over chunks (ctab -> chunk-exclusive prefixes), block-scan of
// 2048 row totals -> bucket-local rowptr + per-bucket partial.
__global__ void scanA(int* __restrict__ ctab, int* __restrict__ rowptr,
                      int* __restrict__ partials) {
  __shared__ int lsum[256];
  int b = blockIdx.x, t = threadIdx.x;
  int cnt[8];
#pragma unroll
  for (int k = 0; k < 8; ++k) cnt[k] = 0;
  for (int c = 0; c < kMC; ++c) {
    int* p = ctab + (size_t)(b * kMC + c) * kRowsPerBkt;
#pragma unroll
    for (int k = 0; k < 8; ++k) {
      int idx = t * 8 + k;
      int v = p[idx];
      p[idx] = cnt[k];
      cnt[k] += v;
    }
  }
  int s = 0, pref[8];
#pragma unroll
  for (int k = 0; k < 8; ++k) { pref[k] = s; s += cnt[k]; }
  lsum[t] = s;
  __syncthreads();
  for (int o = 1; o < 256; o <<= 1) {
    int v = (t >= o) ? lsum[t - o] : 0;
    __syncthreads();
    if (t >= o) lsum[t] += v;
    __syncthreads();
  }
  int ex = (t == 0) ? 0 : lsum[t - 1];
#pragma unroll
  for (int k = 0; k < 8; ++k) {
    int r = b * kRowsPerBkt + t * 8 + k;
    if (r < kN) rowptr[r] = ex + pref[k];
  }
  if (t == 255) partials[b] = lsum[255];
}

__global__ void scan2(int* __restrict__ partials) {
  __shared__ int lds[256];
  int t = threadIdx.x;
  lds[t] = (t < kNBKT) ? partials[t] : 0;
  __syncthreads();
  for (int o = 1; o < 256; o <<= 1) {
    int v = (t >= o) ? lds[t - o] : 0;
    __syncthreads();
    if (t >= o) lds[t] += v;
    __syncthreads();
  }
  int ex = (t == 0) ? 0 : lds[t - 1];
  if (t < kNBKT) partials[t] = ex;
}

__global__ void scan3(int* __restrict__ rowptr, const int* __restrict__ partials) {
  int i = blockIdx.x * blockDim.x + threadIdx.x;
  if (i < kN) rowptr[i] += partials[i >> 11];
  else if (i == kN) rowptr[kN] = kNNZ;
}

// Grid = kNBKT*kMC. Place edges to final CSR slots; random writes confined to
// the bucket's ~272 KB window.
__global__ void chunk_place(const int* __restrict__ gpos, const int2* __restrict__ tmp,
                            const int* __restrict__ rowptr, const int* __restrict__ ctab,
                            int2* __restrict__ edges) {
  __shared__ int rank[kRowsPerBkt];
  int b = blockIdx.x / kMC, c = blockIdx.x % kMC;
  int t = threadIdx.x;
  for (int i = t; i < kRowsPerBkt; i += 256) rank[i] = 0;
  __syncthreads();
  int s = b * kCap + c * kCE;
  int e = b * kCap + gpos[b];
  if (s + kCE < e) e = s + kCE;
  const int* coff = ctab + (size_t)blockIdx.x * kRowsPerBkt;
  for (int j = s + t; j < e; j += 256) {
    int2 epk = tmp[j];
    int rl = epk.x >> 19;
    int k = atomicAdd(&rank[rl], 1);
    int dst = rowptr[b * kRowsPerBkt + rl] + coff[rl] + k;
    edges[dst] = make_int2(epk.x & 0x7FFFF, epk.y);
  }
}

// --- degree counting-sort: order[] groups rows of equal degree together so
// each spmm wave's 8 rows have (nearly) identical trip counts.
__global__ void deg_hist(const int* __restrict__ rowptr, int* __restrict__ dbin) {
  __shared__ int h[kDB];
  int t = threadIdx.x;
  if (t < kDB) h[t] = 0;
  __syncthreads();
  int i = blockIdx.x * 256 + t;
  if (i < kN) {
    int d = min(rowptr[i + 1] - rowptr[i], kDB - 1);
    atomicAdd(&h[d], 1);
  }
  __syncthreads();
  if (t < kDB && h[t]) atomicAdd(&dbin[t], h[t]);
}

__global__ void deg_scan(int* __restrict__ dbin, int* __restrict__ dcur) {
  __shared__ int lds[kDB];
  int t = threadIdx.x;   // 64 threads
  lds[t] = dbin[t];
  __syncthreads();
  for (int o = 1; o < kDB; o <<= 1) {
    int v = (t >= o) ? lds[t - o] : 0;
    __syncthreads();
    if (t >= o) lds[t] += v;
    __syncthreads();
  }
  int ex = (t == 0) ? 0 : lds[t - 1];
  dcur[t] = ex;
}

__global__ void deg_place(const int* __restrict__ rowptr, int* __restrict__ dcur,
                          int* __restrict__ order) {
  __shared__ int h[kDB];
  __shared__ int base[kDB];
  int t = threadIdx.x;
  if (t < kDB) h[t] = 0;
  __syncthreads();
  int i = blockIdx.x * 256 + t;
  int d = -1, rk = 0;
  if (i < kN) {
    d = min(rowptr[i + 1] - rowptr[i], kDB - 1);
    rk = atomicAdd(&h[d], 1);
  }
  __syncthreads();
  if (t < kDB) base[t] = h[t] ? atomicAdd(&dcur[t], h[t]) : 0;
  __syncthreads();
  if (i < kN) order[base[d] + rk] = i;
}

// Convert concat(uemb, iemb) rows to fp16. One thread per 4 elems.
__global__ void to_half(const float* __restrict__ ue, const float* __restrict__ ie,
                        __half* __restrict__ xh) {
  int t = blockIdx.x * blockDim.x + threadIdx.x;
  if (t >= kN * kD / 4) return;
  int row = t >> 4;
  int g = t & 15;
  const float* src = (row < kUsers) ? (ue + (size_t)row * kD)
                                    : (ie + (size_t)(row - kUsers) * kD);
  float4 v = ((const float4*)src)[g];
  __half2 h01 = __float22half2_rn(make_float2(v.x, v.y));
  __half2 h23 = __float22half2_rn(make_float2(v.z, v.w));
  ((int2*)xh)[t] = make_int2(*(int*)&h01, *(int*)&h23);
}

// Reduction-free spmm over degree-sorted rows: one 8-lane group per row
// (8 rows/wave, all ~equal degree). Lane l owns dims [8l, 8l+8); unroll x4
// -> 4 independent 128 B row-gathers in flight per group.
__global__ void spmm(const int* __restrict__ rowptr, const int* __restrict__ order,
                     const int2* __restrict__ edges, const __half* __restrict__ x,
                     __half* __restrict__ yh) {
  int t = threadIdx.x;
  int l = t & 7;                               // dim octet
  int wid = (blockIdx.x * 256 + t) >> 6;       // global wave id
  int g = (t >> 3) & 7;                        // group (row) within wave
  int p = wid * 8 + g;
  int r = (p < kN) ? order[p] : -1;
  int s = 0, e = 0;
  if (r >= 0) { s = rowptr[r]; e = rowptr[r + 1]; }
  int mx = e - s;
#pragma unroll
  for (int m = 8; m <= 32; m <<= 1) mx = max(mx, __shfl_xor(mx, m, 64));
  float acc[8];
#pragma unroll
  for (int k = 0; k < 8; ++k) acc[k] = 0.f;
  int last = max(e - 1, 0);
  int j = s;
  for (int it = 0; it < mx; it += 4) {
    int2 ee[4];
    int4 hh[4];
    float vv[4];
#pragma unroll
    for (int k = 0; k < 4; ++k) {
      int jk = min(j + k, last);
      ee[k] = edges[jk];
      vv[k] = (j + k < e) ? __int_as_float(ee[k].y) : 0.f;
      hh[k] = ((const int4*)(x + (size_t)ee[k].x * kD))[l];
    }
#pragma unroll
    for (int k = 0; k < 4; ++k) {
      const __half2* ph = (const __half2*)&hh[k];
#pragma unroll
      for (int q = 0; q < 4; ++q) {
        acc[2 * q]     = fmaf(vv[k], __half2float(__low2half(ph[q])),  acc[2 * q]);
        acc[2 * q + 1] = fmaf(vv[k], __half2float(__high2half(ph[q])), acc[2 * q + 1]);
      }
    }
    j += 4;
  }
  if (r >= 0) {
    int4 pk;
    __half2* ph = (__half2*)&pk;
#pragma unroll
    for (int k = 0; k < 4; ++k)
      ph[k] = __float22half2_rn(make_float2(acc[2 * k], acc[2 * k + 1]));
    ((int4*)yh)[(size_t)r * 8 + l] = pk;
  }
}

__global__ void acc_init(const int* __restrict__ users, const int* __restrict__ items,
                         const float* __restrict__ uemb, const float* __restrict__ iemb,
                         float* __restrict__ uacc, float* __restrict__ iacc) {
  int tid = blockIdx.x * blockDim.x + threadIdx.x;
  if (tid >= kB * kD) return;
  int b = tid >> 6, d = tid & 63;
  uacc[tid] = uemb[(size_t)users[b] * kD + d];
  iacc[tid] = iemb[(size_t)items[b] * kD + d];
}

// Accumulate the fp16 layer output into the fp32 per-pair accumulators.
__global__ void acc_add(const int* __restrict__ users, const int* __restrict__ items,
                        const __half* __restrict__ xh, float* __restrict__ uacc,
                        float* __restrict__ iacc) {
  int tid = blockIdx.x * blockDim.x + threadIdx.x;
  if (tid >= kB * kD) return;
  int b = tid >> 6, d = tid & 63;
  uacc[tid] += __half2float(xh[(size_t)users[b] * kD + d]);
  iacc[tid] += __half2float(xh[(size_t)(kUsers + items[b]) * kD + d]);
}

// gamma[b] = dot(acc_u, acc_i) / 16
__global__ void finalize(const float* __restrict__ uacc, const float* __restrict__ iacc,
                         float* __restrict__ out) {
  int tid = blockIdx.x * blockDim.x + threadIdx.x;
  if (tid >= kB * kD) return;
  int b = tid >> 6, d = tid & 63;
  float p = uacc[tid] * iacc[tid];
  for (int o = 32; o > 0; o >>= 1) p += __shfl_down(p, o, 64);
  if (d == 0) out[b] = p * 0.0625f;
}

}  // namespace

extern "C" void kernel_launch(void* const* d_in, const int* in_sizes, int n_in,
                              void* d_out, int out_size, void* d_ws, size_t ws_size,
                              hipStream_t stream) {
  const int*   users = (const int*)d_in[0];
  const int*   items = (const int*)d_in[1];
  const int*   erow  = (const int*)d_in[2];
  const int*   ecol  = (const int*)d_in[3];
  const float* evals = (const float*)d_in[4];
  const float* uemb  = (const float*)d_in[5];
  const float* iemb  = (const float*)d_in[6];
  float* out = (float*)d_out;

  char* ws = (char*)d_ws;
  size_t off = 0;
  auto take = [&](size_t bytes) -> char* {
    char* p = ws + off;
    off = (off + bytes + 255) & ~(size_t)255;
    return p;
  };
  int*    rowptr   = (int*)take((size_t)(kN + 1) * 4);
  int*    gpos     = (int*)take((kNBKT + 1 + 2 * kDB) * 4);  // gpos | dbin | dcur
  int*    dbin     = gpos + kNBKT + 1;
  int*    dcur     = dbin + kDB;
  int*    partials = (int*)take(256 * 4);
  int*    order    = (int*)take((size_t)kN * 4);
  int2*   edges    = (int2*)take((size_t)kNNZ * 8);
  int2*   tmp      = (int2*)take((size_t)kNBKT * kCap * 8);  // 48.2 MB
  __half* xh0      = (__half*)take((size_t)kN * kD * 2);     // fp16 ping
  __half* xh1      = (__half*)take((size_t)kN * kD * 2);     // fp16 pong
  float*  uacc     = (float*)take((size_t)kB * kD * 4);
  float*  iacc     = (float*)take((size_t)kB * kD * 4);
  int*    ctab     = (int*)xh0;   // 6.0 MB, dead before to_half writes xh0
  (void)ws_size; (void)in_sizes; (void)n_in; (void)out_size;

  const int nScatBlocks = (kNNZ + kSEPB - 1) / kSEPB;  // 1221
  const int nSpmmBlocks = (kN + 31) / 32;              // 8 rows/wave, 4 waves/block
  const int nRowBlocks  = (kN + 255) / 256;

  // --- CSR build: fixed-capacity bucket sort, then parallel counting sort ---
  zero_i32<<<1, 512, 0, stream>>>(gpos, kNBKT + 1 + 2 * kDB);
  bucket_scatter<<<nScatBlocks, 256, 0, stream>>>(erow, ecol, evals, gpos, tmp);
  chunk_hist<<<kNBKT * kMC, 256, 0, stream>>>(gpos, tmp, ctab);
  scanA<<<kNBKT, 256, 0, stream>>>(ctab, rowptr, partials);
  scan2<<<1, 256, 0, stream>>>(partials);
  scan3<<<(kN + 1 + 255) / 256, 256, 0, stream>>>(rowptr, partials);
  chunk_place<<<kNBKT * kMC, 256, 0, stream>>>(gpos, tmp, rowptr, ctab, edges);

  // --- degree counting-sort of rows (uniform spmm waves) ---
  deg_hist<<<nRowBlocks, 256, 0, stream>>>(rowptr, dbin);
  deg_scan<<<1, kDB, 0, stream>>>(dbin, dcur);
  deg_place<<<nRowBlocks, 256, 0, stream>>>(rowptr, dcur, order);

  // --- fp16 copy of concat embeddings (after chunk_place: ctab aliases xh0) ---
  to_half<<<(kN * kD / 4 + 255) / 256, 256, 0, stream>>>(uemb, iemb, xh0);
  acc_init<<<(kB * kD) / 256, 256, 0, stream>>>(users, items, uemb, iemb, uacc, iacc);

  // --- 3 propagation layers; fp16 ping-pong ---
  spmm<<<nSpmmBlocks, 256, 0, stream>>>(rowptr, order, edges, xh0, xh1);
  acc_add<<<(kB * kD) / 256, 256, 0, stream>>>(users, items, xh1, uacc, iacc);
  spmm<<<nSpmmBlocks, 256, 0, stream>>>(rowptr, order, edges, xh1, xh0);
  acc_add<<<(kB * kD) / 256, 256, 0, stream>>>(users, items, xh0, uacc, iacc);
  spmm<<<nSpmmBlocks, 256, 0, stream>>>(rowptr, order, edges, xh0, xh1);
  acc_add<<<(kB * kD) / 256, 256, 0, stream>>>(users, items, xh1, uacc, iacc);

  finalize<<<(kB * kD) / 256, 256, 0, stream>>>(uacc, iacc, out);
}

// Round 10
// 607.404 us; speedup vs baseline: 1.1176x; 1.1176x over previous
//
#include <hip/hip_runtime.h>
#include <hip/hip_fp16.h>

namespace {

constexpr int kUsers = 100000;
constexpr int kItems = 200000;
constexpr int kN     = kUsers + kItems;   // 300000
constexpr int kD     = 64;
constexpr int kNNZ   = 5000000;
constexpr int kB     = 16384;
constexpr int kRowsPerBkt = 2048;                       // rows per coarse bucket
constexpr int kNBKT  = (kN + kRowsPerBkt - 1) / kRowsPerBkt;  // 147
constexpr int kSEPB  = 4096;                            // edges per bucket_scatter block
constexpr int kCE    = 8192;                            // edges per finalize chunk
constexpr int kMC    = 5;                               // chunks per bucket
constexpr int kCap   = kMC * kCE;                       // 40960 slots/bucket (mean 34133, sd 185)
constexpr int kMaxSub = 2 * kB;                         // upper bound on marked rows

__global__ void zero_i32(int* __restrict__ p, int n) {
  int i = blockIdx.x * blockDim.x + threadIdx.x;
  if (i < n) p[i] = 0;
}

// Counting-sort partition of 4096 edges into 147 coarse buckets; per-wave LDS
// histograms (4x147) cut same-address atomic serialization 4x. LDS staging so
// tmp writes go out in coalesced bucket-run bursts.
// Packed edge: .x = (rowlocal<<19)|col, .y = val bits.
__global__ void bucket_scatter(const int* __restrict__ row, const int* __restrict__ col,
                               const float* __restrict__ val, int* __restrict__ gpos,
                               int2* __restrict__ tmp) {
  __shared__ int hcnt[4][kNBKT];   // per-wave counts -> wave-exclusive offsets
  __shared__ int lofs[kNBKT];
  __shared__ int hbase[kNBKT];
  __shared__ int lds[256];
  __shared__ int2 se[kSEPB];
  __shared__ unsigned short sb[kSEPB];
  int t = threadIdx.x;
  int wv = t >> 6;
  long base = (long)blockIdx.x * kSEPB;
  int valid = (int)min((long)kSEPB, (long)kNNZ - base);
  for (int i = t; i < kNBKT; i += 256) {
    hcnt[0][i] = 0; hcnt[1][i] = 0; hcnt[2][i] = 0; hcnt[3][i] = 0;
  }
  __syncthreads();
  int pk[16], bk[16], rk[16];
  float v[16];
  bool ok[16];
#pragma unroll
  for (int j = 0; j < 16; ++j) {
    long i = base + j * 256 + t;
    ok[j] = (i < kNNZ);
    if (ok[j]) {
      int r = row[i];
      bk[j] = r >> 11;
      pk[j] = ((r & 2047) << 19) | col[i];
      v[j] = val[i];
      rk[j] = atomicAdd(&hcnt[wv][bk[j]], 1);
    }
  }
  __syncthreads();
  // per-bucket: wave-exclusive offsets + total; then block scan of totals
  int own = 0;
  if (t < kNBKT) {
    int c0 = hcnt[0][t], c1 = hcnt[1][t], c2 = hcnt[2][t], c3 = hcnt[3][t];
    hcnt[0][t] = 0; hcnt[1][t] = c0; hcnt[2][t] = c0 + c1; hcnt[3][t] = c0 + c1 + c2;
    own = c0 + c1 + c2 + c3;
  }
  lds[t] = own;
  __syncthreads();
  for (int o = 1; o < 256; o <<= 1) {
    int x = (t >= o) ? lds[t - o] : 0;
    __syncthreads();
    if (t >= o) lds[t] += x;
    __syncthreads();
  }
  if (t < kNBKT) {
    lofs[t] = lds[t] - own;
    hbase[t] = t * kCap + atomicAdd(&gpos[t], own);
  }
  __syncthreads();
  // place into LDS in bucket-sorted order
#pragma unroll
  for (int j = 0; j < 16; ++j) {
    if (ok[j]) {
      int pos = lofs[bk[j]] + hcnt[wv][bk[j]] + rk[j];
      se[pos] = make_int2(pk[j], __float_as_int(v[j]));
      sb[pos] = (unsigned short)bk[j];
    }
  }
  __syncthreads();
  // drain LDS sequentially -> coalesced global runs
#pragma unroll
  for (int j = 0; j < 16; ++j) {
    int pos = t + j * 256;
    if (pos < valid) {
      int b = sb[pos];
      tmp[hbase[b] + (pos - lofs[b])] = se[pos];
    }
  }
}

// Grid = kNBKT*kMC. Per-(bucket,chunk) 2048-row LDS histogram -> ctab.
__global__ void chunk_hist(const int* __restrict__ gpos, const int2* __restrict__ tmp,
                           int* __restrict__ ctab) {
  __shared__ int h[kRowsPerBkt];
  int b = blockIdx.x / kMC, c = blockIdx.x % kMC;
  int t = threadIdx.x;
  for (int i = t; i < kRowsPerBkt; i += 256) h[i] = 0;
  __syncthreads();
  int s = b * kCap + c * kCE;
  int e = b * kCap + gpos[b];
  if (s + kCE < e) e = s + kCE;
  for (int j = s + t; j < e; j += 256) atomicAdd(&h[tmp[j].x >> 19], 1);
  __syncthreads();
  int* dst = ctab + (size_t)blockIdx.x * kRowsPerBkt;
  for (int i = t; i < kRowsPerBkt; i += 256) dst[i] = h[i];
}

// Per-row totals over chunks (ctab -> chunk-exclusive prefixes), block-scan of
// 2048 row totals -> bucket-local rowptr + per-bucket partial.
__global__ void scanA(int* __restrict__ ctab, int* __restrict__ rowptr,
                      int* __restrict__ partials) {
  __shared__ int lsum[256];
  int b = blockIdx.x, t = threadIdx.x;
  int cnt[8];
#pragma unroll
  for (int k = 0; k < 8; ++k) cnt[k] = 0;
  for (int c = 0; c < kMC; ++c) {
    int* p = ctab + (size_t)(b * kMC + c) * kRowsPerBkt;
#pragma unroll
    for (int k = 0; k < 8; ++k) {
      int idx = t * 8 + k;
      int v = p[idx];
      p[idx] = cnt[k];
      cnt[k] += v;
    }
  }
  int s = 0, pref[8];
#pragma unroll
  for (int k = 0; k < 8; ++k) { pref[k] = s; s += cnt[k]; }
  lsum[t] = s;
  __syncthreads();
  for (int o = 1; o < 256; o <<= 1) {
    int v = (t >= o) ? lsum[t - o] : 0;
    __syncthreads();
    if (t >= o) lsum[t] += v;
    __syncthreads();
  }
  int ex = (t == 0) ? 0 : lsum[t - 1];
#pragma unroll
  for (int k = 0; k < 8; ++k) {
    int r = b * kRowsPerBkt + t * 8 + k;
    if (r < kN) rowptr[r] = ex + pref[k];
  }
  if (t == 255) partials[b] = lsum[255];
}

__global__ void scan2(int* __restrict__ partials) {
  __shared__ int lds[256];
  int t = threadIdx.x;
  lds[t] = (t < kNBKT) ? partials[t] : 0;
  __syncthreads();
  for (int o = 1; o < 256; o <<= 1) {
    int v = (t >= o) ? lds[t - o] : 0;
    __syncthreads();
    if (t >= o) lds[t] += v;
    __syncthreads();
  }
  int ex = (t == 0) ? 0 : lds[t - 1];
  if (t < kNBKT) partials[t] = ex;
}

__global__ void scan3(int* __restrict__ rowptr, const int* __restrict__ partials) {
  int i = blockIdx.x * blockDim.x + threadIdx.x;
  if (i < kN) rowptr[i] += partials[i >> 11];
  else if (i == kN) rowptr[kN] = kNNZ;
}

// Grid = kNBKT*kMC. Place edges to final CSR slots; random writes confined to
// the bucket's ~272 KB window.
__global__ void chunk_place(const int* __restrict__ gpos, const int2* __restrict__ tmp,
                            const int* __restrict__ rowptr, const int* __restrict__ ctab,
                            int2* __restrict__ edges) {
  __shared__ int rank[kRowsPerBkt];
  int b = blockIdx.x / kMC, c = blockIdx.x % kMC;
  int t = threadIdx.x;
  for (int i = t; i < kRowsPerBkt; i += 256) rank[i] = 0;
  __syncthreads();
  int s = b * kCap + c * kCE;
  int e = b * kCap + gpos[b];
  if (s + kCE < e) e = s + kCE;
  const int* coff = ctab + (size_t)blockIdx.x * kRowsPerBkt;
  for (int j = s + t; j < e; j += 256) {
    int2 epk = tmp[j];
    int rl = epk.x >> 19;
    int k = atomicAdd(&rank[rl], 1);
    int dst = rowptr[b * kRowsPerBkt + rl] + coff[rl] + k;
    edges[dst] = make_int2(epk.x & 0x7FFFF, epk.y);
  }
}

// --- layer-3 pruning: mark rows actually read by acc_add, compact to a list.
__global__ void mark_rows(const int* __restrict__ users, const int* __restrict__ items,
                          int* __restrict__ mark) {
  int i = blockIdx.x * blockDim.x + threadIdx.x;
  if (i >= kB) return;
  mark[users[i]] = 1;
  mark[kUsers + items[i]] = 1;
}

__global__ void compact_rows(const int* __restrict__ mark, int* __restrict__ list,
                             int* __restrict__ cnt) {
  int i = blockIdx.x * blockDim.x + threadIdx.x;
  if (i < kN && mark[i]) list[atomicAdd(cnt, 1)] = i;
}

// Convert concat(uemb, iemb) rows to fp16. One thread per 4 elems.
__global__ void to_half(const float* __restrict__ ue, const float* __restrict__ ie,
                        __half* __restrict__ xh) {
  int t = blockIdx.x * blockDim.x + threadIdx.x;
  if (t >= kN * kD / 4) return;
  int row = t >> 4;
  int g = t & 15;
  const float* src = (row < kUsers) ? (ue + (size_t)row * kD)
                                    : (ie + (size_t)(row - kUsers) * kD);
  float4 v = ((const float4*)src)[g];
  __half2 h01 = __float22half2_rn(make_float2(v.x, v.y));
  __half2 h23 = __float22half2_rn(make_float2(v.z, v.w));
  ((int2*)xh)[t] = make_int2(*(int*)&h01, *(int*)&h23);
}

// Reduction-free spmm: one 8-lane group per row (8 rows/wave, sequential row
// order for edge-read locality). Lane l owns dims [8l, 8l+8) -> gathers its
// own int4 (16 B), accumulates the full row in registers, coalesced 128 B
// store. Loop to wave-max degree with clamped addresses + zeroed weights.
// SUBSET=true processes only rows in list[0..*cnt).
template <bool SUBSET>
__global__ void spmm(const int* __restrict__ rowptr, const int2* __restrict__ edges,
                     const __half* __restrict__ x, __half* __restrict__ yh,
                     const int* __restrict__ list, const int* __restrict__ cnt) {
  int t = threadIdx.x;
  int l = t & 7;                               // dim octet
  int wid = (blockIdx.x * 256 + t) >> 6;       // global wave id
  int g = (t >> 3) & 7;                        // group (row) within wave
  int p = wid * 8 + g;
  int r;
  if (SUBSET) {
    int n = *cnt;
    r = (p < n) ? list[p] : -1;
  } else {
    r = (p < kN) ? p : -1;
  }
  int s = 0, e = 0;
  if (r >= 0) { s = rowptr[r]; e = rowptr[r + 1]; }
  int mx = e - s;
#pragma unroll
  for (int m = 8; m <= 32; m <<= 1) mx = max(mx, __shfl_xor(mx, m, 64));
  float acc[8];
#pragma unroll
  for (int k = 0; k < 8; ++k) acc[k] = 0.f;
  int last = max(e - 1, 0);
  int j = s;
  for (int it = 0; it < mx; it += 2) {
    int j0 = min(j, last);
    int j1 = min(j + 1, last);
    int2 e0 = edges[j0];
    int2 e1 = edges[j1];
    float v0 = (j < e) ? __int_as_float(e0.y) : 0.f;
    float v1 = (j + 1 < e) ? __int_as_float(e1.y) : 0.f;
    int4 h0 = ((const int4*)(x + (size_t)e0.x * kD))[l];
    int4 h1 = ((const int4*)(x + (size_t)e1.x * kD))[l];
    const __half2* p0 = (const __half2*)&h0;
    const __half2* p1 = (const __half2*)&h1;
#pragma unroll
    for (int k = 0; k < 4; ++k) {
      acc[2 * k]     = fmaf(v0, __half2float(__low2half(p0[k])),  acc[2 * k]);
      acc[2 * k + 1] = fmaf(v0, __half2float(__high2half(p0[k])), acc[2 * k + 1]);
    }
#pragma unroll
    for (int k = 0; k < 4; ++k) {
      acc[2 * k]     = fmaf(v1, __half2float(__low2half(p1[k])),  acc[2 * k]);
      acc[2 * k + 1] = fmaf(v1, __half2float(__high2half(p1[k])), acc[2 * k + 1]);
    }
    j += 2;
  }
  if (r >= 0) {
    int4 pk;
    __half2* ph = (__half2*)&pk;
#pragma unroll
    for (int k = 0; k < 4; ++k)
      ph[k] = __float22half2_rn(make_float2(acc[2 * k], acc[2 * k + 1]));
    ((int4*)yh)[(size_t)r * 8 + l] = pk;
  }
}

__global__ void acc_init(const int* __restrict__ users, const int* __restrict__ items,
                         const float* __restrict__ uemb, const float* __restrict__ iemb,
                         float* __restrict__ uacc, float* __restrict__ iacc) {
  int tid = blockIdx.x * blockDim.x + threadIdx.x;
  if (tid >= kB * kD) return;
  int b = tid >> 6, d = tid & 63;
  uacc[tid] = uemb[(size_t)users[b] * kD + d];
  iacc[tid] = iemb[(size_t)items[b] * kD + d];
}

// Accumulate the fp16 layer output into the fp32 per-pair accumulators.
__global__ void acc_add(const int* __restrict__ users, const int* __restrict__ items,
                        const __half* __restrict__ xh, float* __restrict__ uacc,
                        float* __restrict__ iacc) {
  int tid = blockIdx.x * blockDim.x + threadIdx.x;
  if (tid >= kB * kD) return;
  int b = tid >> 6, d = tid & 63;
  uacc[tid] += __half2float(xh[(size_t)users[b] * kD + d]);
  iacc[tid] += __half2float(xh[(size_t)(kUsers + items[b]) * kD + d]);
}

// gamma[b] = dot(acc_u, acc_i) / 16
__global__ void finalize(const float* __restrict__ uacc, const float* __restrict__ iacc,
                         float* __restrict__ out) {
  int tid = blockIdx.x * blockDim.x + threadIdx.x;
  if (tid >= kB * kD) return;
  int b = tid >> 6, d = tid & 63;
  float p = uacc[tid] * iacc[tid];
  for (int o = 32; o > 0; o >>= 1) p += __shfl_down(p, o, 64);
  if (d == 0) out[b] = p * 0.0625f;
}

}  // namespace

extern "C" void kernel_launch(void* const* d_in, const int* in_sizes, int n_in,
                              void* d_out, int out_size, void* d_ws, size_t ws_size,
                              hipStream_t stream) {
  const int*   users = (const int*)d_in[0];
  const int*   items = (const int*)d_in[1];
  const int*   erow  = (const int*)d_in[2];
  const int*   ecol  = (const int*)d_in[3];
  const float* evals = (const float*)d_in[4];
  const float* uemb  = (const float*)d_in[5];
  const float* iemb  = (const float*)d_in[6];
  float* out = (float*)d_out;

  char* ws = (char*)d_ws;
  size_t off = 0;
  auto take = [&](size_t bytes) -> char* {
    char* p = ws + off;
    off = (off + bytes + 255) & ~(size_t)255;
    return p;
  };
  int*    rowptr   = (int*)take((size_t)(kN + 1) * 4);
  int*    gpos     = (int*)take((kNBKT + 1) * 4);
  int*    partials = (int*)take(256 * 4);
  int*    mark     = (int*)take((size_t)kN * 4);
  int*    list     = (int*)take((size_t)kMaxSub * 4);
  int*    scnt     = (int*)take(256);
  int2*   edges    = (int2*)take((size_t)kNNZ * 8);
  int2*   tmp      = (int2*)take((size_t)kNBKT * kCap * 8);  // 48.2 MB
  __half* xh0      = (__half*)take((size_t)kN * kD * 2);     // fp16 ping
  __half* xh1      = (__half*)take((size_t)kN * kD * 2);     // fp16 pong
  float*  uacc     = (float*)take((size_t)kB * kD * 4);
  float*  iacc     = (float*)take((size_t)kB * kD * 4);
  int*    ctab     = (int*)xh0;   // 6.0 MB, dead before to_half writes xh0
  (void)ws_size; (void)in_sizes; (void)n_in; (void)out_size;

  const int nScatBlocks = (kNNZ + kSEPB - 1) / kSEPB;  // 1221
  const int nSpmmBlocks = (kN + 31) / 32;              // 8 rows/wave, 4 waves/block
  const int nSubBlocks  = (kMaxSub + 31) / 32;         // 1024

  // --- CSR build: fixed-capacity bucket sort, then parallel counting sort ---
  zero_i32<<<1, 256, 0, stream>>>(gpos, kNBKT + 1);
  zero_i32<<<(kN + 255) / 256, 256, 0, stream>>>(mark, kN);
  zero_i32<<<1, 64, 0, stream>>>(scnt, 1);
  bucket_scatter<<<nScatBlocks, 256, 0, stream>>>(erow, ecol, evals, gpos, tmp);
  chunk_hist<<<kNBKT * kMC, 256, 0, stream>>>(gpos, tmp, ctab);
  scanA<<<kNBKT, 256, 0, stream>>>(ctab, rowptr, partials);
  scan2<<<1, 256, 0, stream>>>(partials);
  scan3<<<(kN + 1 + 255) / 256, 256, 0, stream>>>(rowptr, partials);
  chunk_place<<<kNBKT * kMC, 256, 0, stream>>>(gpos, tmp, rowptr, ctab, edges);

  // --- layer-3 row subset (rows read by acc_add) ---
  mark_rows<<<(kB + 255) / 256, 256, 0, stream>>>(users, items, mark);
  compact_rows<<<(kN + 255) / 256, 256, 0, stream>>>(mark, list, scnt);

  // --- fp16 copy of concat embeddings (after chunk_place: ctab aliases xh0) ---
  to_half<<<(kN * kD / 4 + 255) / 256, 256, 0, stream>>>(uemb, iemb, xh0);
  acc_init<<<(kB * kD) / 256, 256, 0, stream>>>(users, items, uemb, iemb, uacc, iacc);

  // --- 3 propagation layers; fp16 ping-pong; layer 3 pruned to subset ---
  spmm<false><<<nSpmmBlocks, 256, 0, stream>>>(rowptr, edges, xh0, xh1, nullptr, nullptr);
  acc_add<<<(kB * kD) / 256, 256, 0, stream>>>(users, items, xh1, uacc, iacc);
  spmm<false><<<nSpmmBlocks, 256, 0, stream>>>(rowptr, edges, xh1, xh0, nullptr, nullptr);
  acc_add<<<(kB * kD) / 256, 256, 0, stream>>>(users, items, xh0, uacc, iacc);
  spmm<true ><<<nSubBlocks, 256, 0, stream>>>(rowptr, edges, xh0, xh1, list, scnt);
  acc_add<<<(kB * kD) / 256, 256, 0, stream>>>(users, items, xh1, uacc, iacc);

  finalize<<<(kB * kD) / 256, 256, 0, stream>>>(uacc, iacc, out);
}